// Round 10
// baseline (961.381 us; speedup 1.0000x reference)
//
#include <hip/hip_runtime.h>
#include <hip/hip_bf16.h>
#include <math.h>

#define NNODES 50000
#define NEDGES 800000
#define NGRAPH 512
#define FIN    256
#define H1     256
#define H2     256
#define H3     512
#define FPOUT  2048

typedef __attribute__((ext_vector_type(8))) short short8;
typedef __attribute__((ext_vector_type(4))) float floatx4;
typedef __attribute__((ext_vector_type(4))) unsigned short ushx4;

// bf16 round-to-nearest-even of a float, returned as raw bits
__device__ inline ushort bf16_rne(float x) {
    unsigned u = __float_as_uint(x);
    u = (u + 0x7FFFu + ((u >> 16) & 1u)) >> 16;
    return (ushort)u;
}
// split a = hi + lo, hi = truncate-to-bf16 (exact float), lo = bf16_rne(residual)
__device__ inline void split2(float a, ushort& h, ushort& l) {
    unsigned u = __float_as_uint(a);
    unsigned hb = u & 0xFFFF0000u;
    h = (ushort)(hb >> 16);
    l = bf16_rne(a - __uint_as_float(hb));
}
__device__ inline float bfu(ushort u) { return __uint_as_float(((unsigned)u) << 16); }

// ---------------- utility kernels ----------------

__global__ __launch_bounds__(256) void zero_i32(int* p, int n) {
    int i = blockIdx.x * 256 + threadIdx.x;
    if (i < n) p[i] = 0;
}

__global__ __launch_bounds__(256) void count_deg(const int* __restrict__ ei, int* __restrict__ degi, int e_total) {
    int e = blockIdx.x * 256 + threadIdx.x;
    if (e >= e_total) return;
    int d = ei[e_total + e];
    atomicAdd(&degi[d], 1);
}

__global__ __launch_bounds__(256) void calc_dis(const int* __restrict__ degi, float* __restrict__ dis, int n) {
    int i = blockIdx.x * 256 + threadIdx.x;
    if (i < n) dis[i] = rsqrtf((float)(degi[i] + 1));   // +1 self loop
}

__global__ __launch_bounds__(256) void scanA(const int* __restrict__ degi, int* __restrict__ offs,
                                             int* __restrict__ partials, int n) {
    __shared__ int sm[256];
    int t = threadIdx.x, idx = blockIdx.x * 256 + t;
    int v = (idx < n) ? degi[idx] : 0;
    sm[t] = v; __syncthreads();
    for (int d = 1; d < 256; d <<= 1) {
        int add = (t >= d) ? sm[t - d] : 0;
        __syncthreads();
        sm[t] += add;
        __syncthreads();
    }
    if (idx < n) offs[idx + 1] = sm[t];
    if (t == 255) partials[blockIdx.x] = sm[255];
}

__global__ __launch_bounds__(256) void scanB(int* __restrict__ partials, int nb) {
    __shared__ int sm[256];
    int t = threadIdx.x;
    int v = (t < nb) ? partials[t] : 0;
    sm[t] = v; __syncthreads();
    for (int d = 1; d < 256; d <<= 1) {
        int add = (t >= d) ? sm[t - d] : 0;
        __syncthreads();
        sm[t] += add;
        __syncthreads();
    }
    if (t < nb) partials[t] = sm[t] - v;   // exclusive
}

__global__ __launch_bounds__(256) void scanC(int* __restrict__ offs, const int* __restrict__ partials, int n) {
    int idx = blockIdx.x * 256 + threadIdx.x;
    if (idx < n) offs[idx + 1] += partials[blockIdx.x];
    if (idx == 0) offs[0] = 0;
}

__global__ __launch_bounds__(256) void copy_i32(const int* __restrict__ a, int* __restrict__ b, int n) {
    int i = blockIdx.x * 256 + threadIdx.x;
    if (i < n) b[i] = a[i];
}

__global__ __launch_bounds__(256) void fill_csr(const int* __restrict__ ei, const float* __restrict__ dis,
                                                int* __restrict__ curs, int* __restrict__ csr_src,
                                                float* __restrict__ csr_w, int e_total) {
    int e = blockIdx.x * 256 + threadIdx.x;
    if (e >= e_total) return;
    int s = ei[e];
    int d = ei[e_total + e];
    int pos = atomicAdd(&curs[d], 1);
    csr_src[pos] = s;
    csr_w[pos] = dis[s] * dis[d];
}

// W[K][N] fp32 -> Wt_hi[N][K], Wt_lo[N][K]: LDS-tiled transpose, coalesced both sides
__global__ __launch_bounds__(256) void wsplit_t(const float* __restrict__ W, ushort* __restrict__ hi,
                                                ushort* __restrict__ lo, int K, int N) {
    __shared__ float sm[32][33];
    int tx = threadIdx.x & 31, ty = threadIdx.x >> 5;   // 32 x 8
    int n0 = blockIdx.x * 32, k0 = blockIdx.y * 32;
    #pragma unroll
    for (int j = 0; j < 32; j += 8)
        sm[ty + j][tx] = W[(size_t)(k0 + ty + j) * N + n0 + tx];
    __syncthreads();
    #pragma unroll
    for (int j = 0; j < 32; j += 8) {
        float a = sm[tx][ty + j];
        ushort h, l; split2(a, h, l);
        size_t o = (size_t)(n0 + ty + j) * K + k0 + tx;
        hi[o] = h; lo[o] = l;
    }
}

// x[total*4 floats] -> hi/lo bf16 tables
__global__ __launch_bounds__(256) void split_x(const float* __restrict__ x, ushort* __restrict__ hi,
                                               ushort* __restrict__ lo, int total4) {
    int i = blockIdx.x * 256 + threadIdx.x;
    if (i >= total4) return;
    float4 a = ((const float4*)x)[i];
    ushort hx, lx, hy, ly, hz, lz, hw, lw;
    split2(a.x, hx, lx); split2(a.y, hy, ly); split2(a.z, hz, lz); split2(a.w, hw, lw);
    ushx4 h = {hx, hy, hz, hw};
    ushx4 l = {lx, ly, lz, lw};
    ((ushx4*)hi)[i] = h;
    ((ushx4*)lo)[i] = l;
}

// ---------------- MFMA split-bf16 GEMM ----------------
// C = relu((Ahi+Alo)(Bhi+Blo)^T + bias); out_hl=1 -> emit Chi/Clo bf16 tables instead of fp32.
#define LSTR 40   // LDS row stride in ushort (32 data + 8 pad)
__global__ __launch_bounds__(256) void gemm_hl(const ushort* __restrict__ Ahi, const ushort* __restrict__ Alo,
                                               const ushort* __restrict__ Bhi, const ushort* __restrict__ Blo,
                                               float* __restrict__ C, ushort* __restrict__ Chi,
                                               ushort* __restrict__ Clo, const float* __restrict__ bias,
                                               int M, int N, int K, int do_relu, int out_hl) {
    __shared__ ushort lsAh[128 * LSTR];
    __shared__ ushort lsAl[128 * LSTR];
    __shared__ ushort lsBh[128 * LSTR];
    __shared__ ushort lsBl[128 * LSTR];
    int tid = threadIdx.x;
    int w = tid >> 6, lane = tid & 63;
    int quad = lane >> 4, lr = lane & 15;
    int wm = w & 1, wn = w >> 1;
    int row0 = blockIdx.y * 128, col0 = blockIdx.x * 128;

    floatx4 acc[4][4];
    #pragma unroll
    for (int i = 0; i < 4; ++i)
        #pragma unroll
        for (int j = 0; j < 4; ++j)
            acc[i][j] = (floatx4){0.f, 0.f, 0.f, 0.f};

    const short8 zer = {0, 0, 0, 0, 0, 0, 0, 0};
    int srow = tid >> 2;
    int skk  = (tid & 3) * 8;

    for (int k0 = 0; k0 < K; k0 += 32) {
        #pragma unroll
        for (int c = 0; c < 2; ++c) {
            int row = c * 64 + srow;
            size_t aoff = (size_t)(row0 + row) * K + k0 + skk;
            bool mok = (row0 + row) < M;
            short8 ah = mok ? __builtin_nontemporal_load((const short8*)(Ahi + aoff)) : zer;
            short8 al = mok ? __builtin_nontemporal_load((const short8*)(Alo + aoff)) : zer;
            size_t boff = (size_t)(col0 + row) * K + k0 + skk;
            short8 bh = *(const short8*)(Bhi + boff);
            short8 bl = *(const short8*)(Blo + boff);
            int lo = row * LSTR + skk;
            *(short8*)(lsAh + lo) = ah;
            *(short8*)(lsAl + lo) = al;
            *(short8*)(lsBh + lo) = bh;
            *(short8*)(lsBl + lo) = bl;
        }
        __syncthreads();
        short8 afh[4], afl[4];
        #pragma unroll
        for (int mt = 0; mt < 4; ++mt) {
            int ao = (wm * 64 + mt * 16 + lr) * LSTR + quad * 8;
            afh[mt] = *(const short8*)(lsAh + ao);
            afl[mt] = *(const short8*)(lsAl + ao);
        }
        #pragma unroll
        for (int nt = 0; nt < 4; ++nt) {
            int bo = (wn * 64 + nt * 16 + lr) * LSTR + quad * 8;
            short8 bfh = *(const short8*)(lsBh + bo);
            short8 bfl = *(const short8*)(lsBl + bo);
            #pragma unroll
            for (int mt = 0; mt < 4; ++mt) {
                acc[mt][nt] = __builtin_amdgcn_mfma_f32_16x16x32_bf16(afh[mt], bfh, acc[mt][nt], 0, 0, 0);
                acc[mt][nt] = __builtin_amdgcn_mfma_f32_16x16x32_bf16(afh[mt], bfl, acc[mt][nt], 0, 0, 0);
                acc[mt][nt] = __builtin_amdgcn_mfma_f32_16x16x32_bf16(afl[mt], bfh, acc[mt][nt], 0, 0, 0);
            }
        }
        __syncthreads();
    }

    #pragma unroll
    for (int mt = 0; mt < 4; ++mt) {
        #pragma unroll
        for (int r = 0; r < 4; ++r) {
            int row = row0 + wm * 64 + mt * 16 + quad * 4 + r;
            if (row >= M) continue;
            #pragma unroll
            for (int nt = 0; nt < 4; ++nt) {
                int col = col0 + wn * 64 + nt * 16 + lr;
                float v = acc[mt][nt][r] + bias[col];
                if (do_relu) v = v > 0.f ? v : 0.f;
                if (out_hl) {
                    ushort h, l; split2(v, h, l);
                    Chi[(size_t)row * N + col] = h;
                    Clo[(size_t)row * N + col] = l;
                } else {
                    C[(size_t)row * N + col] = v;
                }
            }
        }
    }
}

// ---------------- aggregation v6: split-table gather (hi sweep, then lo sweep) ----------------
// y[v] = sum_{s->v} (xhi[s]+xlo[s])*w + (xhi[v]+xlo[v])*dis[v]^2, accumulated fp32.
// Each sweep's hot set = one 25.6 MB bf16 table. Per-wave loop = R7 structure (8 in flight).
__device__ inline void gather_sweep(const ushort* __restrict__ tab, float4& acc, float selfw, int v,
                                    int beg, int end, int lane,
                                    const int* __restrict__ csr_src, const float* __restrict__ csr_w) {
    constexpr int F = 256;
    ushx4 sv = ((const ushx4*)(tab + (size_t)v * F))[lane];
    acc.x += bfu(sv.x) * selfw; acc.y += bfu(sv.y) * selfw;
    acc.z += bfu(sv.z) * selfw; acc.w += bfu(sv.w) * selfw;
    int i = beg;
    for (; i + 8 <= end; i += 8) {
        int   s[8];
        float w[8];
        #pragma unroll
        for (int u = 0; u < 8; ++u) { s[u] = csr_src[i + u]; w[u] = csr_w[i + u]; }
        ushx4 g[8];
        #pragma unroll
        for (int u = 0; u < 8; ++u)
            g[u] = ((const ushx4*)(tab + (size_t)s[u] * F))[lane];
        #pragma unroll
        for (int u = 0; u < 8; ++u) {
            acc.x += bfu(g[u].x) * w[u]; acc.y += bfu(g[u].y) * w[u];
            acc.z += bfu(g[u].z) * w[u]; acc.w += bfu(g[u].w) * w[u];
        }
    }
    for (; i + 2 <= end; i += 2) {
        int s0 = csr_src[i], s1 = csr_src[i + 1];
        float w0 = csr_w[i], w1 = csr_w[i + 1];
        ushx4 g0 = ((const ushx4*)(tab + (size_t)s0 * F))[lane];
        ushx4 g1 = ((const ushx4*)(tab + (size_t)s1 * F))[lane];
        acc.x += bfu(g0.x) * w0 + bfu(g1.x) * w1;
        acc.y += bfu(g0.y) * w0 + bfu(g1.y) * w1;
        acc.z += bfu(g0.z) * w0 + bfu(g1.z) * w1;
        acc.w += bfu(g0.w) * w0 + bfu(g1.w) * w1;
    }
    if (i < end) {
        int s0 = csr_src[i];
        float w0 = csr_w[i];
        ushx4 g0 = ((const ushx4*)(tab + (size_t)s0 * F))[lane];
        acc.x += bfu(g0.x) * w0; acc.y += bfu(g0.y) * w0;
        acc.z += bfu(g0.z) * w0; acc.w += bfu(g0.w) * w0;
    }
}

__global__ __launch_bounds__(256) void agg256s(const ushort* __restrict__ xhi, const ushort* __restrict__ xlo,
                                               ushort* __restrict__ yhi, ushort* __restrict__ ylo,
                                               const float* __restrict__ dis,
                                               const int* __restrict__ offs, const int* __restrict__ csr_src,
                                               const float* __restrict__ csr_w) {
    constexpr int F = 256;
    int wave = threadIdx.x >> 6;
    int lane = threadIdx.x & 63;
    int v = __builtin_amdgcn_readfirstlane(blockIdx.x * 4 + wave);
    if (v >= NNODES) return;
    int beg = __builtin_amdgcn_readfirstlane(offs[v]);
    int end = __builtin_amdgcn_readfirstlane(offs[v + 1]);
    float dv = dis[v];
    float selfw = dv * dv;

    float4 acc = make_float4(0.f, 0.f, 0.f, 0.f);
    gather_sweep(xhi, acc, selfw, v, beg, end, lane, csr_src, csr_w);
    gather_sweep(xlo, acc, selfw, v, beg, end, lane, csr_src, csr_w);

    ushort hx, lx, hy, ly, hz, lz, hw, lw;
    split2(acc.x, hx, lx);
    split2(acc.y, hy, ly);
    split2(acc.z, hz, lz);
    split2(acc.w, hw, lw);
    ushx4 h = {hx, hy, hz, hw};
    ushx4 l = {lx, ly, lz, lw};
    ((ushx4*)(yhi + (size_t)v * F))[lane] = h;
    ((ushx4*)(ylo + (size_t)v * F))[lane] = l;
}

// ---------------- fused gate+pool: per graph, wave per node ----------------
__global__ __launch_bounds__(256) void gatepool(const float* __restrict__ x, const float* __restrict__ pw,
                                                const float* __restrict__ pb, const int* __restrict__ batch,
                                                ushort* __restrict__ phi, ushort* __restrict__ plo, int n) {
    int g = blockIdx.x;
    int t = threadIdx.x;
    int wave = t >> 6, lane = t & 63;
    int lo_ = 0, hi_ = n;
    while (lo_ < hi_) { int mid = (lo_ + hi_) >> 1; if (batch[mid] < g) lo_ = mid + 1; else hi_ = mid; }
    int start = lo_;
    hi_ = n;
    while (lo_ < hi_) { int mid = (lo_ + hi_) >> 1; if (batch[mid] < g + 1) lo_ = mid + 1; else hi_ = mid; }
    int end = lo_;

    const float4* pwv = (const float4*)pw;
    float4 wa = pwv[lane], wb = pwv[lane + 64];
    float pb0 = pb[0];

    float4 s0 = make_float4(0.f, 0.f, 0.f, 0.f), s1 = s0;
    float4 m0 = make_float4(-INFINITY, -INFINITY, -INFINITY, -INFINITY), m1 = m0;

    for (int nn = start + wave; nn < end; nn += 4) {
        const float4* xr = (const float4*)(x + (size_t)nn * 512);
        float4 a = xr[lane];
        float4 b = xr[lane + 64];
        float p = a.x * wa.x + a.y * wa.y + a.z * wa.z + a.w * wa.w
                + b.x * wb.x + b.y * wb.y + b.z * wb.z + b.w * wb.w;
        #pragma unroll
        for (int off = 32; off; off >>= 1) p += __shfl_down(p, off, 64);
        float wg = __shfl(p, 0, 64);
        wg = 1.f / (1.f + expf(-(wg + pb0)));
        s0.x += a.x * wg; s0.y += a.y * wg; s0.z += a.z * wg; s0.w += a.w * wg;
        s1.x += b.x * wg; s1.y += b.y * wg; s1.z += b.z * wg; s1.w += b.w * wg;
        m0.x = fmaxf(m0.x, a.x); m0.y = fmaxf(m0.y, a.y); m0.z = fmaxf(m0.z, a.z); m0.w = fmaxf(m0.w, a.w);
        m1.x = fmaxf(m1.x, b.x); m1.y = fmaxf(m1.y, b.y); m1.z = fmaxf(m1.z, b.z); m1.w = fmaxf(m1.w, b.w);
    }

    __shared__ float ls[4][1024];
    *(float4*)&ls[wave][lane * 4]       = s0;
    *(float4*)&ls[wave][256 + lane * 4] = s1;
    *(float4*)&ls[wave][512 + lane * 4] = m0;
    *(float4*)&ls[wave][768 + lane * 4] = m1;
    __syncthreads();

    float sa = ls[0][t] + ls[1][t] + ls[2][t] + ls[3][t];
    float sb = ls[0][t + 256] + ls[1][t + 256] + ls[2][t + 256] + ls[3][t + 256];
    float ma = fmaxf(fmaxf(ls[0][512 + t], ls[1][512 + t]), fmaxf(ls[2][512 + t], ls[3][512 + t]));
    float mb = fmaxf(fmaxf(ls[0][768 + t], ls[1][768 + t]), fmaxf(ls[2][768 + t], ls[3][768 + t]));
    if (start >= end) { ma = 0.f; mb = 0.f; }
    ushort h, l;
    size_t base = (size_t)g * 1024;
    split2(sa, h, l); phi[base + t] = h;       plo[base + t] = l;
    split2(sb, h, l); phi[base + 256 + t] = h; plo[base + 256 + t] = l;
    split2(ma, h, l); phi[base + 512 + t] = h; plo[base + 512 + t] = l;
    split2(mb, h, l); phi[base + 768 + t] = h; plo[base + 768 + t] = l;
}

// ---------------- launch ----------------

extern "C" void kernel_launch(void* const* d_in, const int* in_sizes, int n_in,
                              void* d_out, int out_size, void* d_ws, size_t ws_size,
                              hipStream_t stream) {
    const float* x0    = (const float*)d_in[0];
    const int*   ei    = (const int*)d_in[1];
    const int*   batch = (const int*)d_in[2];
    const float* W1 = (const float*)d_in[3];
    const float* b1 = (const float*)d_in[4];
    const float* W2 = (const float*)d_in[5];
    const float* b2 = (const float*)d_in[6];
    const float* W3 = (const float*)d_in[7];
    const float* b3 = (const float*)d_in[8];
    const float* pw = (const float*)d_in[9];
    const float* pb = (const float*)d_in[10];
    const float* Wo = (const float*)d_in[11];
    const float* bo = (const float*)d_in[12];
    float* out = (float*)d_out;

    // workspace layout (float units, 16B-aligned regions)
    float* ws = (float*)d_ws;
    size_t off = 0;
    float* bufB = ws + off; off += (size_t)NNODES * 512;                 // x3 fp32 (gatepool input)
    ushort* xhi = (ushort*)(ws + off); off += (size_t)NNODES * 256 / 2;  // activation tables
    ushort* xlo = (ushort*)(ws + off); off += (size_t)NNODES * 256 / 2;
    ushort* yhi = (ushort*)(ws + off); off += (size_t)NNODES * 256 / 2;  // agg output
    ushort* ylo = (ushort*)(ws + off); off += (size_t)NNODES * 256 / 2;
    ushort* W1thi = (ushort*)(ws + off); off += 256 * 256 / 2;
    ushort* W1tlo = (ushort*)(ws + off); off += 256 * 256 / 2;
    ushort* W2thi = (ushort*)(ws + off); off += 256 * 256 / 2;
    ushort* W2tlo = (ushort*)(ws + off); off += 256 * 256 / 2;
    ushort* W3thi = (ushort*)(ws + off); off += 512 * 256 / 2;
    ushort* W3tlo = (ushort*)(ws + off); off += 512 * 256 / 2;
    ushort* Wothi = (ushort*)(ws + off); off += (size_t)FPOUT * 1024 / 2;
    ushort* Wotlo = (ushort*)(ws + off); off += (size_t)FPOUT * 1024 / 2;
    ushort* phi = (ushort*)(ws + off); off += (size_t)NGRAPH * 1024 / 2;
    ushort* plo = (ushort*)(ws + off); off += (size_t)NGRAPH * 1024 / 2;
    float* dis  = ws + off; off += NNODES;
    int*   degi = (int*)(ws + off); off += NNODES;
    int*   offs = (int*)(ws + off); off += (NNODES + 4);
    int*   curs = (int*)(ws + off); off += NNODES;
    int*   csr_src = (int*)(ws + off); off += NEDGES;
    float* csr_w   = ws + off; off += NEDGES;
    int*   partials = (int*)(ws + off); off += 256;

    const int NB_N = (NNODES + 255) / 256;   // 196
    const int NB_E = (NEDGES + 255) / 256;
    const int NB_W = (NNODES + 3) / 4;       // wave per node (12500)
    const int MB128 = (NNODES + 127) / 128;  // 391

    // weight transpose+split (LDS-tiled, coalesced)
    { dim3 g(256 / 32, 256 / 32);  wsplit_t<<<g, 256, 0, stream>>>(W1, W1thi, W1tlo, 256, 256); }
    { dim3 g(256 / 32, 256 / 32);  wsplit_t<<<g, 256, 0, stream>>>(W2, W2thi, W2tlo, 256, 256); }
    { dim3 g(512 / 32, 256 / 32);  wsplit_t<<<g, 256, 0, stream>>>(W3, W3thi, W3tlo, 256, 512); }
    { dim3 g(FPOUT / 32, 1024 / 32); wsplit_t<<<g, 256, 0, stream>>>(Wo, Wothi, Wotlo, 1024, FPOUT); }

    // CSR build
    zero_i32<<<NB_N, 256, 0, stream>>>(degi, NNODES);
    count_deg<<<NB_E, 256, 0, stream>>>(ei, degi, NEDGES);
    calc_dis<<<NB_N, 256, 0, stream>>>(degi, dis, NNODES);
    scanA<<<NB_N, 256, 0, stream>>>(degi, offs, partials, NNODES);
    scanB<<<1, 256, 0, stream>>>(partials, NB_N);
    scanC<<<NB_N, 256, 0, stream>>>(offs, partials, NNODES);
    copy_i32<<<NB_N, 256, 0, stream>>>(offs, curs, NNODES);
    fill_csr<<<NB_E, 256, 0, stream>>>(ei, dis, curs, csr_src, csr_w, NEDGES);

    // pre-split x0 into bf16 tables
    split_x<<<(NNODES * 256 / 4 + 255) / 256, 256, 0, stream>>>(x0, xhi, xlo, NNODES * 256 / 4);

    // layer 1: y = A_norm @ x0 ; x1 = relu(y @ W1 + b1) -> bf16 tables
    agg256s<<<NB_W, 256, 0, stream>>>(xhi, xlo, yhi, ylo, dis, offs, csr_src, csr_w);
    {
        dim3 grid(H1 / 128, MB128);
        gemm_hl<<<grid, 256, 0, stream>>>(yhi, ylo, W1thi, W1tlo, nullptr, xhi, xlo, b1, NNODES, H1, FIN, 1, 1);
    }
    // layer 2
    agg256s<<<NB_W, 256, 0, stream>>>(xhi, xlo, yhi, ylo, dis, offs, csr_src, csr_w);
    {
        dim3 grid(H2 / 128, MB128);
        gemm_hl<<<grid, 256, 0, stream>>>(yhi, ylo, W2thi, W2tlo, nullptr, xhi, xlo, b2, NNODES, H2, H1, 1, 1);
    }
    // layer 3: agg on 256-wide x2 tables, GEMM 256->512 fp32 (gatepool input)
    agg256s<<<NB_W, 256, 0, stream>>>(xhi, xlo, yhi, ylo, dis, offs, csr_src, csr_w);
    {
        dim3 grid(H3 / 128, MB128);
        gemm_hl<<<grid, 256, 0, stream>>>(yhi, ylo, W3thi, W3tlo, bufB, nullptr, nullptr, b3, NNODES, H3, H2, 1, 0);
    }
    // fused gate+pool -> pooled bf16 hi/lo
    gatepool<<<NGRAPH, 256, 0, stream>>>(bufB, pw, pb, batch, phi, plo, NNODES);
    // head: out = relu(pooled @ Wo + bo) via MFMA
    {
        dim3 grid(FPOUT / 128, (NGRAPH + 127) / 128);
        gemm_hl<<<grid, 256, 0, stream>>>(phi, plo, Wothi, Wotlo, out, nullptr, nullptr, bo, NGRAPH, FPOUT, 1024, 1, 0);
    }
}

// Round 11
// 802.735 us; speedup vs baseline: 1.1976x; 1.1976x over previous
//
#include <hip/hip_runtime.h>
#include <hip/hip_bf16.h>
#include <math.h>

#define NNODES 50000
#define NEDGES 800000
#define NGRAPH 512
#define FIN    256
#define H1     256
#define H2     256
#define H3     512
#define FPOUT  2048

typedef __attribute__((ext_vector_type(8))) short short8;
typedef __attribute__((ext_vector_type(4))) float floatx4;
typedef __attribute__((ext_vector_type(4))) unsigned short ushx4;

// bf16 round-to-nearest-even of a float, returned as raw bits
__device__ inline ushort bf16_rne(float x) {
    unsigned u = __float_as_uint(x);
    u = (u + 0x7FFFu + ((u >> 16) & 1u)) >> 16;
    return (ushort)u;
}
// split a = hi + lo, hi = truncate-to-bf16 (exact float), lo = bf16_rne(residual)
__device__ inline void split2(float a, ushort& h, ushort& l) {
    unsigned u = __float_as_uint(a);
    unsigned hb = u & 0xFFFF0000u;
    h = (ushort)(hb >> 16);
    l = bf16_rne(a - __uint_as_float(hb));
}

// ---------------- utility kernels ----------------

__global__ __launch_bounds__(256) void zero_i32(int* p, int n) {
    int i = blockIdx.x * 256 + threadIdx.x;
    if (i < n) p[i] = 0;
}

__global__ __launch_bounds__(256) void count_deg(const int* __restrict__ ei, int* __restrict__ degi, int e_total) {
    int e = blockIdx.x * 256 + threadIdx.x;
    if (e >= e_total) return;
    int d = ei[e_total + e];
    atomicAdd(&degi[d], 1);
}

__global__ __launch_bounds__(256) void calc_dis(const int* __restrict__ degi, float* __restrict__ dis, int n) {
    int i = blockIdx.x * 256 + threadIdx.x;
    if (i < n) dis[i] = rsqrtf((float)(degi[i] + 1));   // +1 self loop
}

__global__ __launch_bounds__(256) void scanA(const int* __restrict__ degi, int* __restrict__ offs,
                                             int* __restrict__ partials, int n) {
    __shared__ int sm[256];
    int t = threadIdx.x, idx = blockIdx.x * 256 + t;
    int v = (idx < n) ? degi[idx] : 0;
    sm[t] = v; __syncthreads();
    for (int d = 1; d < 256; d <<= 1) {
        int add = (t >= d) ? sm[t - d] : 0;
        __syncthreads();
        sm[t] += add;
        __syncthreads();
    }
    if (idx < n) offs[idx + 1] = sm[t];
    if (t == 255) partials[blockIdx.x] = sm[255];
}

__global__ __launch_bounds__(256) void scanB(int* __restrict__ partials, int nb) {
    __shared__ int sm[256];
    int t = threadIdx.x;
    int v = (t < nb) ? partials[t] : 0;
    sm[t] = v; __syncthreads();
    for (int d = 1; d < 256; d <<= 1) {
        int add = (t >= d) ? sm[t - d] : 0;
        __syncthreads();
        sm[t] += add;
        __syncthreads();
    }
    if (t < nb) partials[t] = sm[t] - v;   // exclusive
}

__global__ __launch_bounds__(256) void scanC(int* __restrict__ offs, const int* __restrict__ partials, int n) {
    int idx = blockIdx.x * 256 + threadIdx.x;
    if (idx < n) offs[idx + 1] += partials[blockIdx.x];
    if (idx == 0) offs[0] = 0;
}

__global__ __launch_bounds__(256) void copy_i32(const int* __restrict__ a, int* __restrict__ b, int n) {
    int i = blockIdx.x * 256 + threadIdx.x;
    if (i < n) b[i] = a[i];
}

__global__ __launch_bounds__(256) void fill_csr(const int* __restrict__ ei, const float* __restrict__ dis,
                                                int* __restrict__ curs, int* __restrict__ csr_src,
                                                float* __restrict__ csr_w, int e_total) {
    int e = blockIdx.x * 256 + threadIdx.x;
    if (e >= e_total) return;
    int s = ei[e];
    int d = ei[e_total + e];
    int pos = atomicAdd(&curs[d], 1);
    csr_src[pos] = s;
    csr_w[pos] = dis[s] * dis[d];
}

// W[K][N] fp32 -> Wt_hi[N][K], Wt_lo[N][K]: LDS-tiled transpose, coalesced both sides
__global__ __launch_bounds__(256) void wsplit_t(const float* __restrict__ W, ushort* __restrict__ hi,
                                                ushort* __restrict__ lo, int K, int N) {
    __shared__ float sm[32][33];
    int tx = threadIdx.x & 31, ty = threadIdx.x >> 5;   // 32 x 8
    int n0 = blockIdx.x * 32, k0 = blockIdx.y * 32;
    #pragma unroll
    for (int j = 0; j < 32; j += 8)
        sm[ty + j][tx] = W[(size_t)(k0 + ty + j) * N + n0 + tx];
    __syncthreads();
    #pragma unroll
    for (int j = 0; j < 32; j += 8) {
        float a = sm[tx][ty + j];
        ushort h, l; split2(a, h, l);
        size_t o = (size_t)(n0 + ty + j) * K + k0 + tx;
        hi[o] = h; lo[o] = l;
    }
}

// ---------------- MFMA split-bf16 GEMM: C = relu((Ahi+Alo)(Bhi+Blo)^T + bias) ----------------
// A: [M][K] bf16 bits (hi/lo), B: [N][K] bf16 bits. 128x128 tile, 4 waves,
// wave = 64x64 via 4x4 grid of mfma_f32_16x16x32_bf16. 3-term: hi.hi + hi.lo + lo.hi.
// NOTE: plain (cached) A loads — A fits L3, re-reads across column blocks must hit cache.
#define LSTR 40   // LDS row stride in ushort (32 data + 8 pad)
__global__ __launch_bounds__(256) void gemm_hl(const ushort* __restrict__ Ahi, const ushort* __restrict__ Alo,
                                               const ushort* __restrict__ Bhi, const ushort* __restrict__ Blo,
                                               float* __restrict__ C, const float* __restrict__ bias,
                                               int M, int N, int K, int do_relu) {
    __shared__ ushort lsAh[128 * LSTR];
    __shared__ ushort lsAl[128 * LSTR];
    __shared__ ushort lsBh[128 * LSTR];
    __shared__ ushort lsBl[128 * LSTR];
    int tid = threadIdx.x;
    int w = tid >> 6, lane = tid & 63;
    int quad = lane >> 4, lr = lane & 15;
    int wm = w & 1, wn = w >> 1;
    int row0 = blockIdx.y * 128, col0 = blockIdx.x * 128;

    floatx4 acc[4][4];
    #pragma unroll
    for (int i = 0; i < 4; ++i)
        #pragma unroll
        for (int j = 0; j < 4; ++j)
            acc[i][j] = (floatx4){0.f, 0.f, 0.f, 0.f};

    const short8 zer = {0, 0, 0, 0, 0, 0, 0, 0};
    int srow = tid >> 2;
    int skk  = (tid & 3) * 8;

    for (int k0 = 0; k0 < K; k0 += 32) {
        #pragma unroll
        for (int c = 0; c < 2; ++c) {
            int row = c * 64 + srow;
            size_t aoff = (size_t)(row0 + row) * K + k0 + skk;
            bool mok = (row0 + row) < M;
            short8 ah = mok ? *(const short8*)(Ahi + aoff) : zer;
            short8 al = mok ? *(const short8*)(Alo + aoff) : zer;
            size_t boff = (size_t)(col0 + row) * K + k0 + skk;
            short8 bh = *(const short8*)(Bhi + boff);
            short8 bl = *(const short8*)(Blo + boff);
            int lo = row * LSTR + skk;
            *(short8*)(lsAh + lo) = ah;
            *(short8*)(lsAl + lo) = al;
            *(short8*)(lsBh + lo) = bh;
            *(short8*)(lsBl + lo) = bl;
        }
        __syncthreads();
        short8 afh[4], afl[4];
        #pragma unroll
        for (int mt = 0; mt < 4; ++mt) {
            int ao = (wm * 64 + mt * 16 + lr) * LSTR + quad * 8;
            afh[mt] = *(const short8*)(lsAh + ao);
            afl[mt] = *(const short8*)(lsAl + ao);
        }
        #pragma unroll
        for (int nt = 0; nt < 4; ++nt) {
            int bo = (wn * 64 + nt * 16 + lr) * LSTR + quad * 8;
            short8 bfh = *(const short8*)(lsBh + bo);
            short8 bfl = *(const short8*)(lsBl + bo);
            #pragma unroll
            for (int mt = 0; mt < 4; ++mt) {
                acc[mt][nt] = __builtin_amdgcn_mfma_f32_16x16x32_bf16(afh[mt], bfh, acc[mt][nt], 0, 0, 0);
                acc[mt][nt] = __builtin_amdgcn_mfma_f32_16x16x32_bf16(afh[mt], bfl, acc[mt][nt], 0, 0, 0);
                acc[mt][nt] = __builtin_amdgcn_mfma_f32_16x16x32_bf16(afl[mt], bfh, acc[mt][nt], 0, 0, 0);
            }
        }
        __syncthreads();
    }

    #pragma unroll
    for (int mt = 0; mt < 4; ++mt) {
        #pragma unroll
        for (int r = 0; r < 4; ++r) {
            int row = row0 + wm * 64 + mt * 16 + quad * 4 + r;
            if (row >= M) continue;
            #pragma unroll
            for (int nt = 0; nt < 4; ++nt) {
                int col = col0 + wn * 64 + nt * 16 + lr;
                float v = acc[mt][nt][r] + bias[col];
                if (do_relu) v = v > 0.f ? v : 0.f;
                C[(size_t)row * N + col] = v;
            }
        }
    }
}

// ---------------- aggregation (R7-proven): wave per node, F=256, emits bf16 hi/lo ----------------
// y[v] = sum_{s->v} x[s]*w + x[v]*dis[v]^2   (agg-first reorder: A@(xW) == (A@x)W)
__global__ __launch_bounds__(256) void agg256hl(const float* __restrict__ x, ushort* __restrict__ yhi,
                                                ushort* __restrict__ ylo, const float* __restrict__ dis,
                                                const int* __restrict__ offs, const int* __restrict__ csr_src,
                                                const float* __restrict__ csr_w) {
    constexpr int F = 256;
    constexpr int UNROLL = 8;
    int wave = threadIdx.x >> 6;
    int lane = threadIdx.x & 63;
    int v = __builtin_amdgcn_readfirstlane(blockIdx.x * 4 + wave);
    if (v >= NNODES) return;
    int beg = __builtin_amdgcn_readfirstlane(offs[v]);
    int end = __builtin_amdgcn_readfirstlane(offs[v + 1]);
    float dv = dis[v];
    float selfw = dv * dv;

    const float4* xv = (const float4*)(x + (size_t)v * F);
    float4 a = xv[lane];
    float4 acc = make_float4(a.x * selfw, a.y * selfw, a.z * selfw, a.w * selfw);

    int i = beg;
    for (; i + UNROLL <= end; i += UNROLL) {
        int   s[UNROLL];
        float w[UNROLL];
        #pragma unroll
        for (int u = 0; u < UNROLL; ++u) { s[u] = csr_src[i + u]; w[u] = csr_w[i + u]; }
        float4 g[UNROLL];
        #pragma unroll
        for (int u = 0; u < UNROLL; ++u)
            g[u] = ((const float4*)(x + (size_t)s[u] * F))[lane];
        #pragma unroll
        for (int u = 0; u < UNROLL; ++u) {
            acc.x += g[u].x * w[u]; acc.y += g[u].y * w[u];
            acc.z += g[u].z * w[u]; acc.w += g[u].w * w[u];
        }
    }
    for (; i + 2 <= end; i += 2) {
        int s0 = csr_src[i], s1 = csr_src[i + 1];
        float w0 = csr_w[i], w1 = csr_w[i + 1];
        float4 x0 = ((const float4*)(x + (size_t)s0 * F))[lane];
        float4 x1 = ((const float4*)(x + (size_t)s1 * F))[lane];
        acc.x += x0.x * w0 + x1.x * w1; acc.y += x0.y * w0 + x1.y * w1;
        acc.z += x0.z * w0 + x1.z * w1; acc.w += x0.w * w0 + x1.w * w1;
    }
    if (i < end) {
        int s0 = csr_src[i];
        float w0 = csr_w[i];
        float4 x0 = ((const float4*)(x + (size_t)s0 * F))[lane];
        acc.x += x0.x * w0; acc.y += x0.y * w0; acc.z += x0.z * w0; acc.w += x0.w * w0;
    }

    ushort hx, lx, hy, ly, hz, lz, hw, lw;
    split2(acc.x, hx, lx);
    split2(acc.y, hy, ly);
    split2(acc.z, hz, lz);
    split2(acc.w, hw, lw);
    ushx4 h = {hx, hy, hz, hw};
    ushx4 l = {lx, ly, lz, lw};
    ((ushx4*)(yhi + (size_t)v * F))[lane] = h;
    ((ushx4*)(ylo + (size_t)v * F))[lane] = l;
}

// ---------------- fused gate+pool: per graph, wave per node ----------------
__global__ __launch_bounds__(256) void gatepool(const float* __restrict__ x, const float* __restrict__ pw,
                                                const float* __restrict__ pb, const int* __restrict__ batch,
                                                ushort* __restrict__ phi, ushort* __restrict__ plo, int n) {
    int g = blockIdx.x;
    int t = threadIdx.x;
    int wave = t >> 6, lane = t & 63;
    int lo_ = 0, hi_ = n;
    while (lo_ < hi_) { int mid = (lo_ + hi_) >> 1; if (batch[mid] < g) lo_ = mid + 1; else hi_ = mid; }
    int start = lo_;
    hi_ = n;
    while (lo_ < hi_) { int mid = (lo_ + hi_) >> 1; if (batch[mid] < g + 1) lo_ = mid + 1; else hi_ = mid; }
    int end = lo_;

    const float4* pwv = (const float4*)pw;
    float4 wa = pwv[lane], wb = pwv[lane + 64];
    float pb0 = pb[0];

    float4 s0 = make_float4(0.f, 0.f, 0.f, 0.f), s1 = s0;
    float4 m0 = make_float4(-INFINITY, -INFINITY, -INFINITY, -INFINITY), m1 = m0;

    for (int nn = start + wave; nn < end; nn += 4) {
        const float4* xr = (const float4*)(x + (size_t)nn * 512);
        float4 a = xr[lane];
        float4 b = xr[lane + 64];
        float p = a.x * wa.x + a.y * wa.y + a.z * wa.z + a.w * wa.w
                + b.x * wb.x + b.y * wb.y + b.z * wb.z + b.w * wb.w;
        #pragma unroll
        for (int off = 32; off; off >>= 1) p += __shfl_down(p, off, 64);
        float wg = __shfl(p, 0, 64);
        wg = 1.f / (1.f + expf(-(wg + pb0)));
        s0.x += a.x * wg; s0.y += a.y * wg; s0.z += a.z * wg; s0.w += a.w * wg;
        s1.x += b.x * wg; s1.y += b.y * wg; s1.z += b.z * wg; s1.w += b.w * wg;
        m0.x = fmaxf(m0.x, a.x); m0.y = fmaxf(m0.y, a.y); m0.z = fmaxf(m0.z, a.z); m0.w = fmaxf(m0.w, a.w);
        m1.x = fmaxf(m1.x, b.x); m1.y = fmaxf(m1.y, b.y); m1.z = fmaxf(m1.z, b.z); m1.w = fmaxf(m1.w, b.w);
    }

    __shared__ float ls[4][1024];
    *(float4*)&ls[wave][lane * 4]       = s0;
    *(float4*)&ls[wave][256 + lane * 4] = s1;
    *(float4*)&ls[wave][512 + lane * 4] = m0;
    *(float4*)&ls[wave][768 + lane * 4] = m1;
    __syncthreads();

    float sa = ls[0][t] + ls[1][t] + ls[2][t] + ls[3][t];
    float sb = ls[0][t + 256] + ls[1][t + 256] + ls[2][t + 256] + ls[3][t + 256];
    float ma = fmaxf(fmaxf(ls[0][512 + t], ls[1][512 + t]), fmaxf(ls[2][512 + t], ls[3][512 + t]));
    float mb = fmaxf(fmaxf(ls[0][768 + t], ls[1][768 + t]), fmaxf(ls[2][768 + t], ls[3][768 + t]));
    if (start >= end) { ma = 0.f; mb = 0.f; }
    ushort h, l;
    size_t base = (size_t)g * 1024;
    split2(sa, h, l); phi[base + t] = h;       plo[base + t] = l;
    split2(sb, h, l); phi[base + 256 + t] = h; plo[base + 256 + t] = l;
    split2(ma, h, l); phi[base + 512 + t] = h; plo[base + 512 + t] = l;
    split2(mb, h, l); phi[base + 768 + t] = h; plo[base + 768 + t] = l;
}

// ---------------- launch ----------------

extern "C" void kernel_launch(void* const* d_in, const int* in_sizes, int n_in,
                              void* d_out, int out_size, void* d_ws, size_t ws_size,
                              hipStream_t stream) {
    const float* x0    = (const float*)d_in[0];
    const int*   ei    = (const int*)d_in[1];
    const int*   batch = (const int*)d_in[2];
    const float* W1 = (const float*)d_in[3];
    const float* b1 = (const float*)d_in[4];
    const float* W2 = (const float*)d_in[5];
    const float* b2 = (const float*)d_in[6];
    const float* W3 = (const float*)d_in[7];
    const float* b3 = (const float*)d_in[8];
    const float* pw = (const float*)d_in[9];
    const float* pb = (const float*)d_in[10];
    const float* Wo = (const float*)d_in[11];
    const float* bo = (const float*)d_in[12];
    float* out = (float*)d_out;

    // workspace layout (float units, 16B-aligned regions)
    float* ws = (float*)d_ws;
    size_t off = 0;
    float* bufB = ws + off; off += (size_t)NNODES * 512;                 // layer outputs fp32
    ushort* yhi = (ushort*)(ws + off); off += (size_t)NNODES * 256 / 2;  // agg out hi
    ushort* ylo = (ushort*)(ws + off); off += (size_t)NNODES * 256 / 2;  // agg out lo
    ushort* W1thi = (ushort*)(ws + off); off += 256 * 256 / 2;
    ushort* W1tlo = (ushort*)(ws + off); off += 256 * 256 / 2;
    ushort* W2thi = (ushort*)(ws + off); off += 256 * 256 / 2;
    ushort* W2tlo = (ushort*)(ws + off); off += 256 * 256 / 2;
    ushort* W3thi = (ushort*)(ws + off); off += 512 * 256 / 2;
    ushort* W3tlo = (ushort*)(ws + off); off += 512 * 256 / 2;
    ushort* Wothi = (ushort*)(ws + off); off += (size_t)FPOUT * 1024 / 2;
    ushort* Wotlo = (ushort*)(ws + off); off += (size_t)FPOUT * 1024 / 2;
    ushort* phi = (ushort*)(ws + off); off += (size_t)NGRAPH * 1024 / 2;
    ushort* plo = (ushort*)(ws + off); off += (size_t)NGRAPH * 1024 / 2;
    float* dis  = ws + off; off += NNODES;
    int*   degi = (int*)(ws + off); off += NNODES;
    int*   offs = (int*)(ws + off); off += (NNODES + 4);
    int*   curs = (int*)(ws + off); off += NNODES;
    int*   csr_src = (int*)(ws + off); off += NEDGES;
    float* csr_w   = ws + off; off += NEDGES;
    int*   partials = (int*)(ws + off); off += 256;

    const int NB_N = (NNODES + 255) / 256;   // 196
    const int NB_E = (NEDGES + 255) / 256;
    const int NB_W = (NNODES + 3) / 4;       // wave per node (12500)
    const int MB128 = (NNODES + 127) / 128;  // 391

    // weight transpose+split (LDS-tiled, coalesced)
    { dim3 g(256 / 32, 256 / 32);    wsplit_t<<<g, 256, 0, stream>>>(W1, W1thi, W1tlo, 256, 256); }
    { dim3 g(256 / 32, 256 / 32);    wsplit_t<<<g, 256, 0, stream>>>(W2, W2thi, W2tlo, 256, 256); }
    { dim3 g(512 / 32, 256 / 32);    wsplit_t<<<g, 256, 0, stream>>>(W3, W3thi, W3tlo, 256, 512); }
    { dim3 g(FPOUT / 32, 1024 / 32); wsplit_t<<<g, 256, 0, stream>>>(Wo, Wothi, Wotlo, 1024, FPOUT); }

    // CSR build
    zero_i32<<<NB_N, 256, 0, stream>>>(degi, NNODES);
    count_deg<<<NB_E, 256, 0, stream>>>(ei, degi, NEDGES);
    calc_dis<<<NB_N, 256, 0, stream>>>(degi, dis, NNODES);
    scanA<<<NB_N, 256, 0, stream>>>(degi, offs, partials, NNODES);
    scanB<<<1, 256, 0, stream>>>(partials, NB_N);
    scanC<<<NB_N, 256, 0, stream>>>(offs, partials, NNODES);
    copy_i32<<<NB_N, 256, 0, stream>>>(offs, curs, NNODES);
    fill_csr<<<NB_E, 256, 0, stream>>>(ei, dis, curs, csr_src, csr_w, NEDGES);

    // layer 1: y = A_norm @ x0 (bf16 hi/lo) ; x1 = relu(y @ W1 + b1) via MFMA
    agg256hl<<<NB_W, 256, 0, stream>>>(x0, yhi, ylo, dis, offs, csr_src, csr_w);
    {
        dim3 grid(H1 / 128, MB128);
        gemm_hl<<<grid, 256, 0, stream>>>(yhi, ylo, W1thi, W1tlo, bufB, b1, NNODES, H1, FIN, 1);
    }
    // layer 2
    agg256hl<<<NB_W, 256, 0, stream>>>(bufB, yhi, ylo, dis, offs, csr_src, csr_w);
    {
        dim3 grid(H2 / 128, MB128);
        gemm_hl<<<grid, 256, 0, stream>>>(yhi, ylo, W2thi, W2tlo, bufB, b2, NNODES, H2, H1, 1);
    }
    // layer 3: agg on 256-wide x2, MFMA GEMM 256->512
    agg256hl<<<NB_W, 256, 0, stream>>>(bufB, yhi, ylo, dis, offs, csr_src, csr_w);
    {
        dim3 grid(H3 / 128, MB128);
        gemm_hl<<<grid, 256, 0, stream>>>(yhi, ylo, W3thi, W3tlo, bufB, b3, NNODES, H3, H2, 1);
    }
    // fused gate+pool -> pooled bf16 hi/lo
    gatepool<<<NGRAPH, 256, 0, stream>>>(bufB, pw, pb, batch, phi, plo, NNODES);
    // head: out = relu(pooled @ Wo + bo) via MFMA
    {
        dim3 grid(FPOUT / 128, (NGRAPH + 127) / 128);
        gemm_hl<<<grid, 256, 0, stream>>>(phi, plo, Wothi, Wotlo, out, bo, NGRAPH, FPOUT, 1024, 1);
    }
}

// Round 12
// 672.721 us; speedup vs baseline: 1.4291x; 1.1933x over previous
//
#include <hip/hip_runtime.h>
#include <hip/hip_bf16.h>
#include <math.h>

#define NNODES 50000
#define NEDGES 800000
#define NGRAPH 512
#define FIN    256
#define H1     256
#define H2     256
#define H3     512
#define FPOUT  2048

typedef __attribute__((ext_vector_type(8))) short short8;
typedef __attribute__((ext_vector_type(4))) float floatx4;
typedef __attribute__((ext_vector_type(4))) unsigned short ushx4;

// bf16 round-to-nearest-even of a float, returned as raw bits
__device__ inline ushort bf16_rne(float x) {
    unsigned u = __float_as_uint(x);
    u = (u + 0x7FFFu + ((u >> 16) & 1u)) >> 16;
    return (ushort)u;
}
// split a = hi + lo, hi = truncate-to-bf16 (exact float), lo = bf16_rne(residual)
__device__ inline void split2(float a, ushort& h, ushort& l) {
    unsigned u = __float_as_uint(a);
    unsigned hb = u & 0xFFFF0000u;
    h = (ushort)(hb >> 16);
    l = bf16_rne(a - __uint_as_float(hb));
}
__device__ inline float bfu(ushort u) { return __uint_as_float(((unsigned)u) << 16); }

// ---------------- utility kernels ----------------

__global__ __launch_bounds__(256) void zero_i32(int* p, int n) {
    int i = blockIdx.x * 256 + threadIdx.x;
    if (i < n) p[i] = 0;
}

__global__ __launch_bounds__(256) void count_deg(const int* __restrict__ ei, int* __restrict__ degi, int e_total) {
    int e = blockIdx.x * 256 + threadIdx.x;
    if (e >= e_total) return;
    int d = ei[e_total + e];
    atomicAdd(&degi[d], 1);
}

__global__ __launch_bounds__(256) void calc_dis(const int* __restrict__ degi, float* __restrict__ dis, int n) {
    int i = blockIdx.x * 256 + threadIdx.x;
    if (i < n) dis[i] = rsqrtf((float)(degi[i] + 1));   // +1 self loop
}

__global__ __launch_bounds__(256) void scanA(const int* __restrict__ degi, int* __restrict__ offs,
                                             int* __restrict__ partials, int n) {
    __shared__ int sm[256];
    int t = threadIdx.x, idx = blockIdx.x * 256 + t;
    int v = (idx < n) ? degi[idx] : 0;
    sm[t] = v; __syncthreads();
    for (int d = 1; d < 256; d <<= 1) {
        int add = (t >= d) ? sm[t - d] : 0;
        __syncthreads();
        sm[t] += add;
        __syncthreads();
    }
    if (idx < n) offs[idx + 1] = sm[t];
    if (t == 255) partials[blockIdx.x] = sm[255];
}

__global__ __launch_bounds__(256) void scanB(int* __restrict__ partials, int nb) {
    __shared__ int sm[256];
    int t = threadIdx.x;
    int v = (t < nb) ? partials[t] : 0;
    sm[t] = v; __syncthreads();
    for (int d = 1; d < 256; d <<= 1) {
        int add = (t >= d) ? sm[t - d] : 0;
        __syncthreads();
        sm[t] += add;
        __syncthreads();
    }
    if (t < nb) partials[t] = sm[t] - v;   // exclusive
}

__global__ __launch_bounds__(256) void scanC(int* __restrict__ offs, const int* __restrict__ partials, int n) {
    int idx = blockIdx.x * 256 + threadIdx.x;
    if (idx < n) offs[idx + 1] += partials[blockIdx.x];
    if (idx == 0) offs[0] = 0;
}

__global__ __launch_bounds__(256) void copy_i32(const int* __restrict__ a, int* __restrict__ b, int n) {
    int i = blockIdx.x * 256 + threadIdx.x;
    if (i < n) b[i] = a[i];
}

__global__ __launch_bounds__(256) void fill_csr(const int* __restrict__ ei, const float* __restrict__ dis,
                                                int* __restrict__ curs, int* __restrict__ csr_src,
                                                float* __restrict__ csr_w, int e_total) {
    int e = blockIdx.x * 256 + threadIdx.x;
    if (e >= e_total) return;
    int s = ei[e];
    int d = ei[e_total + e];
    int pos = atomicAdd(&curs[d], 1);
    csr_src[pos] = s;
    csr_w[pos] = dis[s] * dis[d];
}

// W[K][N] fp32 -> Wt_hi[N][K], Wt_lo[N][K]: LDS-tiled transpose, coalesced both sides
__global__ __launch_bounds__(256) void wsplit_t(const float* __restrict__ W, ushort* __restrict__ hi,
                                                ushort* __restrict__ lo, int K, int N) {
    __shared__ float sm[32][33];
    int tx = threadIdx.x & 31, ty = threadIdx.x >> 5;   // 32 x 8
    int n0 = blockIdx.x * 32, k0 = blockIdx.y * 32;
    #pragma unroll
    for (int j = 0; j < 32; j += 8)
        sm[ty + j][tx] = W[(size_t)(k0 + ty + j) * N + n0 + tx];
    __syncthreads();
    #pragma unroll
    for (int j = 0; j < 32; j += 8) {
        float a = sm[tx][ty + j];
        ushort h, l; split2(a, h, l);
        size_t o = (size_t)(n0 + ty + j) * K + k0 + tx;
        hi[o] = h; lo[o] = l;
    }
}

// x fp32 -> bf16-RNE table (for layer-1 agg input)
__global__ __launch_bounds__(256) void conv_bf16(const float* __restrict__ x, ushort* __restrict__ xh, int total4) {
    int i = blockIdx.x * 256 + threadIdx.x;
    if (i >= total4) return;
    float4 a = ((const float4*)x)[i];
    ushx4 h = {bf16_rne(a.x), bf16_rne(a.y), bf16_rne(a.z), bf16_rne(a.w)};
    ((ushx4*)xh)[i] = h;
}

// ---------------- MFMA split-bf16 GEMM ----------------
// C = relu((Ahi+Alo)(Bhi+Blo)^T + bias).
// outmode 0: fp32 C.  outmode 1: bf16-RNE Ch only (activation table for next agg).
#define LSTR 40   // LDS row stride in ushort (32 data + 8 pad)
__global__ __launch_bounds__(256) void gemm_hl(const ushort* __restrict__ Ahi, const ushort* __restrict__ Alo,
                                               const ushort* __restrict__ Bhi, const ushort* __restrict__ Blo,
                                               float* __restrict__ C, ushort* __restrict__ Ch,
                                               const float* __restrict__ bias,
                                               int M, int N, int K, int do_relu, int outmode) {
    __shared__ ushort lsAh[128 * LSTR];
    __shared__ ushort lsAl[128 * LSTR];
    __shared__ ushort lsBh[128 * LSTR];
    __shared__ ushort lsBl[128 * LSTR];
    int tid = threadIdx.x;
    int w = tid >> 6, lane = tid & 63;
    int quad = lane >> 4, lr = lane & 15;
    int wm = w & 1, wn = w >> 1;
    int row0 = blockIdx.y * 128, col0 = blockIdx.x * 128;

    floatx4 acc[4][4];
    #pragma unroll
    for (int i = 0; i < 4; ++i)
        #pragma unroll
        for (int j = 0; j < 4; ++j)
            acc[i][j] = (floatx4){0.f, 0.f, 0.f, 0.f};

    const short8 zer = {0, 0, 0, 0, 0, 0, 0, 0};
    int srow = tid >> 2;
    int skk  = (tid & 3) * 8;

    for (int k0 = 0; k0 < K; k0 += 32) {
        #pragma unroll
        for (int c = 0; c < 2; ++c) {
            int row = c * 64 + srow;
            size_t aoff = (size_t)(row0 + row) * K + k0 + skk;
            bool mok = (row0 + row) < M;
            short8 ah = mok ? *(const short8*)(Ahi + aoff) : zer;
            short8 al = mok ? *(const short8*)(Alo + aoff) : zer;
            size_t boff = (size_t)(col0 + row) * K + k0 + skk;
            short8 bh = *(const short8*)(Bhi + boff);
            short8 bl = *(const short8*)(Blo + boff);
            int lo = row * LSTR + skk;
            *(short8*)(lsAh + lo) = ah;
            *(short8*)(lsAl + lo) = al;
            *(short8*)(lsBh + lo) = bh;
            *(short8*)(lsBl + lo) = bl;
        }
        __syncthreads();
        short8 afh[4], afl[4];
        #pragma unroll
        for (int mt = 0; mt < 4; ++mt) {
            int ao = (wm * 64 + mt * 16 + lr) * LSTR + quad * 8;
            afh[mt] = *(const short8*)(lsAh + ao);
            afl[mt] = *(const short8*)(lsAl + ao);
        }
        #pragma unroll
        for (int nt = 0; nt < 4; ++nt) {
            int bo = (wn * 64 + nt * 16 + lr) * LSTR + quad * 8;
            short8 bfh = *(const short8*)(lsBh + bo);
            short8 bfl = *(const short8*)(lsBl + bo);
            #pragma unroll
            for (int mt = 0; mt < 4; ++mt) {
                acc[mt][nt] = __builtin_amdgcn_mfma_f32_16x16x32_bf16(afh[mt], bfh, acc[mt][nt], 0, 0, 0);
                acc[mt][nt] = __builtin_amdgcn_mfma_f32_16x16x32_bf16(afh[mt], bfl, acc[mt][nt], 0, 0, 0);
                acc[mt][nt] = __builtin_amdgcn_mfma_f32_16x16x32_bf16(afl[mt], bfh, acc[mt][nt], 0, 0, 0);
            }
        }
        __syncthreads();
    }

    #pragma unroll
    for (int mt = 0; mt < 4; ++mt) {
        #pragma unroll
        for (int r = 0; r < 4; ++r) {
            int row = row0 + wm * 64 + mt * 16 + quad * 4 + r;
            if (row >= M) continue;
            #pragma unroll
            for (int nt = 0; nt < 4; ++nt) {
                int col = col0 + wn * 64 + nt * 16 + lr;
                float v = acc[mt][nt][r] + bias[col];
                if (do_relu) v = v > 0.f ? v : 0.f;
                if (outmode) Ch[(size_t)row * N + col] = bf16_rne(v);
                else         C[(size_t)row * N + col] = v;
            }
        }
    }
}

// ---------------- aggregation v7: bf16 gather, 2 nodes per wave ----------------
// y[v] = sum_{s->v} xh[s]*w + xh[v]*dis[v]^2, fp32 accumulate, output hi/lo split.
// Lanes 0-31 -> node v0, lanes 32-63 -> v1: each gather instr covers two full 512B rows.
// Divergent degrees: wave-max trip count, predicated (clamped, w=0) loads.
__global__ __launch_bounds__(256) void agg256b(const ushort* __restrict__ xh, ushort* __restrict__ yhi,
                                               ushort* __restrict__ ylo, const float* __restrict__ dis,
                                               const int* __restrict__ offs, const int* __restrict__ csr_src,
                                               const float* __restrict__ csr_w) {
    constexpr int F = 256;
    int wave = threadIdx.x >> 6;
    int lane = threadIdx.x & 63;
    int half = lane >> 5;
    int sub  = lane & 31;                       // covers ushorts sub*8 .. sub*8+8
    int v = blockIdx.x * 8 + wave * 2 + half;   // 50000 % 8 == 0 -> always < NNODES
    int beg = offs[v], end = offs[v + 1];
    int len = end - beg;
    int leno = __shfl_xor(len, 32, 64);
    int maxlen = len > leno ? len : leno;       // uniform across wave

    float dv = dis[v];
    float sw = dv * dv;
    short8 a0 = ((const short8*)(xh + (size_t)v * F))[sub];
    float acc[8];
    #pragma unroll
    for (int j = 0; j < 8; ++j) acc[j] = bfu((ushort)a0[j]) * sw;

    for (int k = 0; k < maxlen; k += 8) {
        int   s[8];
        float w[8];
        #pragma unroll
        for (int u = 0; u < 8; ++u) {
            int idx = beg + k + u;
            bool val = idx < end;
            int ic = val ? idx : 0;
            s[u] = csr_src[ic];
            w[u] = val ? csr_w[ic] : 0.f;
        }
        short8 g[8];
        #pragma unroll
        for (int u = 0; u < 8; ++u)
            g[u] = ((const short8*)(xh + (size_t)s[u] * F))[sub];
        #pragma unroll
        for (int u = 0; u < 8; ++u) {
            #pragma unroll
            for (int j = 0; j < 8; ++j)
                acc[j] += bfu((ushort)g[u][j]) * w[u];
        }
    }

    ushort h[8], l[8];
    #pragma unroll
    for (int j = 0; j < 8; ++j) split2(acc[j], h[j], l[j]);
    short8 hv = {(short)h[0], (short)h[1], (short)h[2], (short)h[3], (short)h[4], (short)h[5], (short)h[6], (short)h[7]};
    short8 lv = {(short)l[0], (short)l[1], (short)l[2], (short)l[3], (short)l[4], (short)l[5], (short)l[6], (short)l[7]};
    ((short8*)(yhi + (size_t)v * F))[sub] = hv;
    ((short8*)(ylo + (size_t)v * F))[sub] = lv;
}

// ---------------- fused gate+pool: per graph, wave per node ----------------
__global__ __launch_bounds__(256) void gatepool(const float* __restrict__ x, const float* __restrict__ pw,
                                                const float* __restrict__ pb, const int* __restrict__ batch,
                                                ushort* __restrict__ phi, ushort* __restrict__ plo, int n) {
    int g = blockIdx.x;
    int t = threadIdx.x;
    int wave = t >> 6, lane = t & 63;
    int lo_ = 0, hi_ = n;
    while (lo_ < hi_) { int mid = (lo_ + hi_) >> 1; if (batch[mid] < g) lo_ = mid + 1; else hi_ = mid; }
    int start = lo_;
    hi_ = n;
    while (lo_ < hi_) { int mid = (lo_ + hi_) >> 1; if (batch[mid] < g + 1) lo_ = mid + 1; else hi_ = mid; }
    int end = lo_;

    const float4* pwv = (const float4*)pw;
    float4 wa = pwv[lane], wb = pwv[lane + 64];
    float pb0 = pb[0];

    float4 s0 = make_float4(0.f, 0.f, 0.f, 0.f), s1 = s0;
    float4 m0 = make_float4(-INFINITY, -INFINITY, -INFINITY, -INFINITY), m1 = m0;

    for (int nn = start + wave; nn < end; nn += 4) {
        const float4* xr = (const float4*)(x + (size_t)nn * 512);
        float4 a = xr[lane];
        float4 b = xr[lane + 64];
        float p = a.x * wa.x + a.y * wa.y + a.z * wa.z + a.w * wa.w
                + b.x * wb.x + b.y * wb.y + b.z * wb.z + b.w * wb.w;
        #pragma unroll
        for (int off = 32; off; off >>= 1) p += __shfl_down(p, off, 64);
        float wg = __shfl(p, 0, 64);
        wg = 1.f / (1.f + expf(-(wg + pb0)));
        s0.x += a.x * wg; s0.y += a.y * wg; s0.z += a.z * wg; s0.w += a.w * wg;
        s1.x += b.x * wg; s1.y += b.y * wg; s1.z += b.z * wg; s1.w += b.w * wg;
        m0.x = fmaxf(m0.x, a.x); m0.y = fmaxf(m0.y, a.y); m0.z = fmaxf(m0.z, a.z); m0.w = fmaxf(m0.w, a.w);
        m1.x = fmaxf(m1.x, b.x); m1.y = fmaxf(m1.y, b.y); m1.z = fmaxf(m1.z, b.z); m1.w = fmaxf(m1.w, b.w);
    }

    __shared__ float ls[4][1024];
    *(float4*)&ls[wave][lane * 4]       = s0;
    *(float4*)&ls[wave][256 + lane * 4] = s1;
    *(float4*)&ls[wave][512 + lane * 4] = m0;
    *(float4*)&ls[wave][768 + lane * 4] = m1;
    __syncthreads();

    float sa = ls[0][t] + ls[1][t] + ls[2][t] + ls[3][t];
    float sb = ls[0][t + 256] + ls[1][t + 256] + ls[2][t + 256] + ls[3][t + 256];
    float ma = fmaxf(fmaxf(ls[0][512 + t], ls[1][512 + t]), fmaxf(ls[2][512 + t], ls[3][512 + t]));
    float mb = fmaxf(fmaxf(ls[0][768 + t], ls[1][768 + t]), fmaxf(ls[2][768 + t], ls[3][768 + t]));
    if (start >= end) { ma = 0.f; mb = 0.f; }
    ushort h, l;
    size_t base = (size_t)g * 1024;
    split2(sa, h, l); phi[base + t] = h;       plo[base + t] = l;
    split2(sb, h, l); phi[base + 256 + t] = h; plo[base + 256 + t] = l;
    split2(ma, h, l); phi[base + 512 + t] = h; plo[base + 512 + t] = l;
    split2(mb, h, l); phi[base + 768 + t] = h; plo[base + 768 + t] = l;
}

// ---------------- launch ----------------

extern "C" void kernel_launch(void* const* d_in, const int* in_sizes, int n_in,
                              void* d_out, int out_size, void* d_ws, size_t ws_size,
                              hipStream_t stream) {
    const float* x0    = (const float*)d_in[0];
    const int*   ei    = (const int*)d_in[1];
    const int*   batch = (const int*)d_in[2];
    const float* W1 = (const float*)d_in[3];
    const float* b1 = (const float*)d_in[4];
    const float* W2 = (const float*)d_in[5];
    const float* b2 = (const float*)d_in[6];
    const float* W3 = (const float*)d_in[7];
    const float* b3 = (const float*)d_in[8];
    const float* pw = (const float*)d_in[9];
    const float* pb = (const float*)d_in[10];
    const float* Wo = (const float*)d_in[11];
    const float* bo = (const float*)d_in[12];
    float* out = (float*)d_out;

    // workspace layout (float units, 16B-aligned regions)
    float* ws = (float*)d_ws;
    size_t off = 0;
    float* bufB = ws + off; off += (size_t)NNODES * 512;                 // x3 fp32 (gatepool input)
    ushort* xh  = (ushort*)(ws + off); off += (size_t)NNODES * 256 / 2;  // activation bf16 table
    ushort* yhi = (ushort*)(ws + off); off += (size_t)NNODES * 256 / 2;  // agg out hi
    ushort* ylo = (ushort*)(ws + off); off += (size_t)NNODES * 256 / 2;  // agg out lo
    ushort* W1thi = (ushort*)(ws + off); off += 256 * 256 / 2;
    ushort* W1tlo = (ushort*)(ws + off); off += 256 * 256 / 2;
    ushort* W2thi = (ushort*)(ws + off); off += 256 * 256 / 2;
    ushort* W2tlo = (ushort*)(ws + off); off += 256 * 256 / 2;
    ushort* W3thi = (ushort*)(ws + off); off += 512 * 256 / 2;
    ushort* W3tlo = (ushort*)(ws + off); off += 512 * 256 / 2;
    ushort* Wothi = (ushort*)(ws + off); off += (size_t)FPOUT * 1024 / 2;
    ushort* Wotlo = (ushort*)(ws + off); off += (size_t)FPOUT * 1024 / 2;
    ushort* phi = (ushort*)(ws + off); off += (size_t)NGRAPH * 1024 / 2;
    ushort* plo = (ushort*)(ws + off); off += (size_t)NGRAPH * 1024 / 2;
    float* dis  = ws + off; off += NNODES;
    int*   degi = (int*)(ws + off); off += NNODES;
    int*   offs = (int*)(ws + off); off += (NNODES + 4);
    int*   curs = (int*)(ws + off); off += NNODES;
    int*   csr_src = (int*)(ws + off); off += NEDGES;
    float* csr_w   = ws + off; off += NEDGES;
    int*   partials = (int*)(ws + off); off += 256;

    const int NB_N = (NNODES + 255) / 256;   // 196
    const int NB_E = (NEDGES + 255) / 256;
    const int NB_A = NNODES / 8;             // 6250 blocks, wave = 2 nodes
    const int MB128 = (NNODES + 127) / 128;  // 391

    // weight transpose+split (LDS-tiled, coalesced)
    { dim3 g(256 / 32, 256 / 32);    wsplit_t<<<g, 256, 0, stream>>>(W1, W1thi, W1tlo, 256, 256); }
    { dim3 g(256 / 32, 256 / 32);    wsplit_t<<<g, 256, 0, stream>>>(W2, W2thi, W2tlo, 256, 256); }
    { dim3 g(512 / 32, 256 / 32);    wsplit_t<<<g, 256, 0, stream>>>(W3, W3thi, W3tlo, 256, 512); }
    { dim3 g(FPOUT / 32, 1024 / 32); wsplit_t<<<g, 256, 0, stream>>>(Wo, Wothi, Wotlo, 1024, FPOUT); }

    // CSR build
    zero_i32<<<NB_N, 256, 0, stream>>>(degi, NNODES);
    count_deg<<<NB_E, 256, 0, stream>>>(ei, degi, NEDGES);
    calc_dis<<<NB_N, 256, 0, stream>>>(degi, dis, NNODES);
    scanA<<<NB_N, 256, 0, stream>>>(degi, offs, partials, NNODES);
    scanB<<<1, 256, 0, stream>>>(partials, NB_N);
    scanC<<<NB_N, 256, 0, stream>>>(offs, partials, NNODES);
    copy_i32<<<NB_N, 256, 0, stream>>>(offs, curs, NNODES);
    fill_csr<<<NB_E, 256, 0, stream>>>(ei, dis, curs, csr_src, csr_w, NEDGES);

    // x0 -> bf16 table
    conv_bf16<<<(NNODES * 256 / 4 + 255) / 256, 256, 0, stream>>>(x0, xh, NNODES * 256 / 4);

    // layer 1: y = A_norm @ x0h ; x1h = bf16(relu(y @ W1 + b1))
    agg256b<<<NB_A, 256, 0, stream>>>(xh, yhi, ylo, dis, offs, csr_src, csr_w);
    {
        dim3 grid(H1 / 128, MB128);
        gemm_hl<<<grid, 256, 0, stream>>>(yhi, ylo, W1thi, W1tlo, nullptr, xh, b1, NNODES, H1, FIN, 1, 1);
    }
    // layer 2
    agg256b<<<NB_A, 256, 0, stream>>>(xh, yhi, ylo, dis, offs, csr_src, csr_w);
    {
        dim3 grid(H2 / 128, MB128);
        gemm_hl<<<grid, 256, 0, stream>>>(yhi, ylo, W2thi, W2tlo, nullptr, xh, b2, NNODES, H2, H1, 1, 1);
    }
    // layer 3: agg on x2h, GEMM 256->512 -> fp32 (gatepool input)
    agg256b<<<NB_A, 256, 0, stream>>>(xh, yhi, ylo, dis, offs, csr_src, csr_w);
    {
        dim3 grid(H3 / 128, MB128);
        gemm_hl<<<grid, 256, 0, stream>>>(yhi, ylo, W3thi, W3tlo, bufB, nullptr, b3, NNODES, H3, H2, 1, 0);
    }
    // fused gate+pool -> pooled bf16 hi/lo
    gatepool<<<NGRAPH, 256, 0, stream>>>(bufB, pw, pb, batch, phi, plo, NNODES);
    // head: out = relu(pooled @ Wo + bo) via MFMA
    {
        dim3 grid(FPOUT / 128, (NGRAPH + 127) / 128);
        gemm_hl<<<grid, 256, 0, stream>>>(phi, plo, Wothi, Wotlo, out, nullptr, bo, NGRAPH, FPOUT, 1024, 1, 0);
    }
}

// Round 13
// 668.862 us; speedup vs baseline: 1.4373x; 1.0058x over previous
//
#include <hip/hip_runtime.h>
#include <hip/hip_bf16.h>
#include <math.h>

#define NNODES 50000
#define NEDGES 800000
#define NGRAPH 512
#define FIN    256
#define H1     256
#define H2     256
#define H3     512
#define FPOUT  2048

typedef __attribute__((ext_vector_type(8))) short short8;
typedef __attribute__((ext_vector_type(4))) float floatx4;
typedef __attribute__((ext_vector_type(4))) unsigned short ushx4;

// bf16 round-to-nearest-even of a float, returned as raw bits
__device__ inline ushort bf16_rne(float x) {
    unsigned u = __float_as_uint(x);
    u = (u + 0x7FFFu + ((u >> 16) & 1u)) >> 16;
    return (ushort)u;
}
// split a = hi + lo, hi = truncate-to-bf16 (exact float), lo = bf16_rne(residual)
__device__ inline void split2(float a, ushort& h, ushort& l) {
    unsigned u = __float_as_uint(a);
    unsigned hb = u & 0xFFFF0000u;
    h = (ushort)(hb >> 16);
    l = bf16_rne(a - __uint_as_float(hb));
}
__device__ inline float bfu(ushort u) { return __uint_as_float(((unsigned)u) << 16); }

// ---------------- utility kernels ----------------

__global__ __launch_bounds__(256) void zero_i32(int* p, int n) {
    int i = blockIdx.x * 256 + threadIdx.x;
    if (i < n) p[i] = 0;
}

__global__ __launch_bounds__(256) void count_deg(const int* __restrict__ ei, int* __restrict__ degi, int e_total) {
    int e = blockIdx.x * 256 + threadIdx.x;
    if (e >= e_total) return;
    int d = ei[e_total + e];
    atomicAdd(&degi[d], 1);
}

__global__ __launch_bounds__(256) void calc_dis(const int* __restrict__ degi, float* __restrict__ dis, int n) {
    int i = blockIdx.x * 256 + threadIdx.x;
    if (i < n) dis[i] = rsqrtf((float)(degi[i] + 1));   // +1 self loop
}

__global__ __launch_bounds__(256) void scanA(const int* __restrict__ degi, int* __restrict__ offs,
                                             int* __restrict__ partials, int n) {
    __shared__ int sm[256];
    int t = threadIdx.x, idx = blockIdx.x * 256 + t;
    int v = (idx < n) ? degi[idx] : 0;
    sm[t] = v; __syncthreads();
    for (int d = 1; d < 256; d <<= 1) {
        int add = (t >= d) ? sm[t - d] : 0;
        __syncthreads();
        sm[t] += add;
        __syncthreads();
    }
    if (idx < n) offs[idx + 1] = sm[t];
    if (t == 255) partials[blockIdx.x] = sm[255];
}

__global__ __launch_bounds__(256) void scanB(int* __restrict__ partials, int nb) {
    __shared__ int sm[256];
    int t = threadIdx.x;
    int v = (t < nb) ? partials[t] : 0;
    sm[t] = v; __syncthreads();
    for (int d = 1; d < 256; d <<= 1) {
        int add = (t >= d) ? sm[t - d] : 0;
        __syncthreads();
        sm[t] += add;
        __syncthreads();
    }
    if (t < nb) partials[t] = sm[t] - v;   // exclusive
}

__global__ __launch_bounds__(256) void scanC(int* __restrict__ offs, const int* __restrict__ partials, int n) {
    int idx = blockIdx.x * 256 + threadIdx.x;
    if (idx < n) offs[idx + 1] += partials[blockIdx.x];
    if (idx == 0) offs[0] = 0;
}

__global__ __launch_bounds__(256) void copy_i32(const int* __restrict__ a, int* __restrict__ b, int n) {
    int i = blockIdx.x * 256 + threadIdx.x;
    if (i < n) b[i] = a[i];
}

__global__ __launch_bounds__(256) void fill_csr(const int* __restrict__ ei, const float* __restrict__ dis,
                                                int* __restrict__ curs, int* __restrict__ csr_src,
                                                float* __restrict__ csr_w, int e_total) {
    int e = blockIdx.x * 256 + threadIdx.x;
    if (e >= e_total) return;
    int s = ei[e];
    int d = ei[e_total + e];
    int pos = atomicAdd(&curs[d], 1);
    csr_src[pos] = s;
    csr_w[pos] = dis[s] * dis[d];
}

// W[K][N] fp32 -> Wt_hi[N][K], Wt_lo[N][K]: LDS-tiled transpose, coalesced both sides
__global__ __launch_bounds__(256) void wsplit_t(const float* __restrict__ W, ushort* __restrict__ hi,
                                                ushort* __restrict__ lo, int K, int N) {
    __shared__ float sm[32][33];
    int tx = threadIdx.x & 31, ty = threadIdx.x >> 5;   // 32 x 8
    int n0 = blockIdx.x * 32, k0 = blockIdx.y * 32;
    #pragma unroll
    for (int j = 0; j < 32; j += 8)
        sm[ty + j][tx] = W[(size_t)(k0 + ty + j) * N + n0 + tx];
    __syncthreads();
    #pragma unroll
    for (int j = 0; j < 32; j += 8) {
        float a = sm[tx][ty + j];
        ushort h, l; split2(a, h, l);
        size_t o = (size_t)(n0 + ty + j) * K + k0 + tx;
        hi[o] = h; lo[o] = l;
    }
}

// x fp32 -> bf16-RNE table (for layer-1 agg input)
__global__ __launch_bounds__(256) void conv_bf16(const float* __restrict__ x, ushort* __restrict__ xh, int total4) {
    int i = blockIdx.x * 256 + threadIdx.x;
    if (i >= total4) return;
    float4 a = ((const float4*)x)[i];
    ushx4 h = {bf16_rne(a.x), bf16_rne(a.y), bf16_rne(a.z), bf16_rne(a.w)};
    ((ushx4*)xh)[i] = h;
}

// ---------------- MFMA split-bf16 GEMM with register K-chunk prefetch ----------------
// C = relu((Ahi+Alo)(Bhi+Blo)^T + bias).
// outmode 0: fp32 C.  outmode 1: bf16-RNE Ch only (activation table for next agg).
// Next K-chunk's global data is loaded into VGPRs right after the staging barrier,
// overlapping a full iteration of MFMA compute (short-K loop: latency otherwise exposed).
#define LSTR 40   // LDS row stride in ushort (32 data + 8 pad)
__global__ __launch_bounds__(256) void gemm_hl(const ushort* __restrict__ Ahi, const ushort* __restrict__ Alo,
                                               const ushort* __restrict__ Bhi, const ushort* __restrict__ Blo,
                                               float* __restrict__ C, ushort* __restrict__ Ch,
                                               const float* __restrict__ bias,
                                               int M, int N, int K, int do_relu, int outmode) {
    __shared__ ushort lsAh[128 * LSTR];
    __shared__ ushort lsAl[128 * LSTR];
    __shared__ ushort lsBh[128 * LSTR];
    __shared__ ushort lsBl[128 * LSTR];
    int tid = threadIdx.x;
    int w = tid >> 6, lane = tid & 63;
    int quad = lane >> 4, lr = lane & 15;
    int wm = w & 1, wn = w >> 1;
    int row0 = blockIdx.y * 128, col0 = blockIdx.x * 128;

    floatx4 acc[4][4];
    #pragma unroll
    for (int i = 0; i < 4; ++i)
        #pragma unroll
        for (int j = 0; j < 4; ++j)
            acc[i][j] = (floatx4){0.f, 0.f, 0.f, 0.f};

    const short8 zer = {0, 0, 0, 0, 0, 0, 0, 0};
    int srow = tid >> 2;           // 0..63 (chunk adds +64)
    int skk  = (tid & 3) * 8;      // k offset within 32

    short8 pah[2], pal[2], pbh[2], pbl[2];
    // prologue: load k-chunk 0
    #pragma unroll
    for (int c = 0; c < 2; ++c) {
        int row = c * 64 + srow;
        bool mok = (row0 + row) < M;
        size_t aoff = (size_t)(row0 + row) * K + skk;
        pah[c] = mok ? *(const short8*)(Ahi + aoff) : zer;
        pal[c] = mok ? *(const short8*)(Alo + aoff) : zer;
        size_t boff = (size_t)(col0 + row) * K + skk;
        pbh[c] = *(const short8*)(Bhi + boff);
        pbl[c] = *(const short8*)(Blo + boff);
    }

    for (int k0 = 0; k0 < K; k0 += 32) {
        // commit prefetched chunk to LDS
        #pragma unroll
        for (int c = 0; c < 2; ++c) {
            int lo = (c * 64 + srow) * LSTR + skk;
            *(short8*)(lsAh + lo) = pah[c];
            *(short8*)(lsAl + lo) = pal[c];
            *(short8*)(lsBh + lo) = pbh[c];
            *(short8*)(lsBl + lo) = pbl[c];
        }
        __syncthreads();
        // issue next chunk's global loads — overlap with the MFMA section below
        if (k0 + 32 < K) {
            #pragma unroll
            for (int c = 0; c < 2; ++c) {
                int row = c * 64 + srow;
                bool mok = (row0 + row) < M;
                size_t aoff = (size_t)(row0 + row) * K + k0 + 32 + skk;
                pah[c] = mok ? *(const short8*)(Ahi + aoff) : zer;
                pal[c] = mok ? *(const short8*)(Alo + aoff) : zer;
                size_t boff = (size_t)(col0 + row) * K + k0 + 32 + skk;
                pbh[c] = *(const short8*)(Bhi + boff);
                pbl[c] = *(const short8*)(Blo + boff);
            }
        }
        short8 afh[4], afl[4];
        #pragma unroll
        for (int mt = 0; mt < 4; ++mt) {
            int ao = (wm * 64 + mt * 16 + lr) * LSTR + quad * 8;
            afh[mt] = *(const short8*)(lsAh + ao);
            afl[mt] = *(const short8*)(lsAl + ao);
        }
        #pragma unroll
        for (int nt = 0; nt < 4; ++nt) {
            int bo = (wn * 64 + nt * 16 + lr) * LSTR + quad * 8;
            short8 bfh = *(const short8*)(lsBh + bo);
            short8 bfl = *(const short8*)(lsBl + bo);
            #pragma unroll
            for (int mt = 0; mt < 4; ++mt) {
                acc[mt][nt] = __builtin_amdgcn_mfma_f32_16x16x32_bf16(afh[mt], bfh, acc[mt][nt], 0, 0, 0);
                acc[mt][nt] = __builtin_amdgcn_mfma_f32_16x16x32_bf16(afh[mt], bfl, acc[mt][nt], 0, 0, 0);
                acc[mt][nt] = __builtin_amdgcn_mfma_f32_16x16x32_bf16(afl[mt], bfh, acc[mt][nt], 0, 0, 0);
            }
        }
        __syncthreads();
    }

    #pragma unroll
    for (int mt = 0; mt < 4; ++mt) {
        #pragma unroll
        for (int r = 0; r < 4; ++r) {
            int row = row0 + wm * 64 + mt * 16 + quad * 4 + r;
            if (row >= M) continue;
            #pragma unroll
            for (int nt = 0; nt < 4; ++nt) {
                int col = col0 + wn * 64 + nt * 16 + lr;
                float v = acc[mt][nt][r] + bias[col];
                if (do_relu) v = v > 0.f ? v : 0.f;
                if (outmode) Ch[(size_t)row * N + col] = bf16_rne(v);
                else         C[(size_t)row * N + col] = v;
            }
        }
    }
}

// ---------------- aggregation v7: bf16 gather, 2 nodes per wave ----------------
// y[v] = sum_{s->v} xh[s]*w + xh[v]*dis[v]^2, fp32 accumulate, output hi/lo split.
// Lanes 0-31 -> node v0, lanes 32-63 -> v1: each gather instr covers two full 512B rows.
// Divergent degrees: wave-max trip count, predicated (clamped, w=0) loads.
__global__ __launch_bounds__(256) void agg256b(const ushort* __restrict__ xh, ushort* __restrict__ yhi,
                                               ushort* __restrict__ ylo, const float* __restrict__ dis,
                                               const int* __restrict__ offs, const int* __restrict__ csr_src,
                                               const float* __restrict__ csr_w) {
    constexpr int F = 256;
    int wave = threadIdx.x >> 6;
    int lane = threadIdx.x & 63;
    int half = lane >> 5;
    int sub  = lane & 31;                       // covers ushorts sub*8 .. sub*8+8
    int v = blockIdx.x * 8 + wave * 2 + half;   // 50000 % 8 == 0 -> always < NNODES
    int beg = offs[v], end = offs[v + 1];
    int len = end - beg;
    int leno = __shfl_xor(len, 32, 64);
    int maxlen = len > leno ? len : leno;       // uniform across wave

    float dv = dis[v];
    float sw = dv * dv;
    short8 a0 = ((const short8*)(xh + (size_t)v * F))[sub];
    float acc[8];
    #pragma unroll
    for (int j = 0; j < 8; ++j) acc[j] = bfu((ushort)a0[j]) * sw;

    for (int k = 0; k < maxlen; k += 8) {
        int   s[8];
        float w[8];
        #pragma unroll
        for (int u = 0; u < 8; ++u) {
            int idx = beg + k + u;
            bool val = idx < end;
            int ic = val ? idx : 0;
            s[u] = csr_src[ic];
            w[u] = val ? csr_w[ic] : 0.f;
        }
        short8 g[8];
        #pragma unroll
        for (int u = 0; u < 8; ++u)
            g[u] = ((const short8*)(xh + (size_t)s[u] * F))[sub];
        #pragma unroll
        for (int u = 0; u < 8; ++u) {
            #pragma unroll
            for (int j = 0; j < 8; ++j)
                acc[j] += bfu((ushort)g[u][j]) * w[u];
        }
    }

    ushort h[8], l[8];
    #pragma unroll
    for (int j = 0; j < 8; ++j) split2(acc[j], h[j], l[j]);
    short8 hv = {(short)h[0], (short)h[1], (short)h[2], (short)h[3], (short)h[4], (short)h[5], (short)h[6], (short)h[7]};
    short8 lv = {(short)l[0], (short)l[1], (short)l[2], (short)l[3], (short)l[4], (short)l[5], (short)l[6], (short)l[7]};
    ((short8*)(yhi + (size_t)v * F))[sub] = hv;
    ((short8*)(ylo + (size_t)v * F))[sub] = lv;
}

// ---------------- fused gate+pool: per graph, wave per node ----------------
__global__ __launch_bounds__(256) void gatepool(const float* __restrict__ x, const float* __restrict__ pw,
                                                const float* __restrict__ pb, const int* __restrict__ batch,
                                                ushort* __restrict__ phi, ushort* __restrict__ plo, int n) {
    int g = blockIdx.x;
    int t = threadIdx.x;
    int wave = t >> 6, lane = t & 63;
    int lo_ = 0, hi_ = n;
    while (lo_ < hi_) { int mid = (lo_ + hi_) >> 1; if (batch[mid] < g) lo_ = mid + 1; else hi_ = mid; }
    int start = lo_;
    hi_ = n;
    while (lo_ < hi_) { int mid = (lo_ + hi_) >> 1; if (batch[mid] < g + 1) lo_ = mid + 1; else hi_ = mid; }
    int end = lo_;

    const float4* pwv = (const float4*)pw;
    float4 wa = pwv[lane], wb = pwv[lane + 64];
    float pb0 = pb[0];

    float4 s0 = make_float4(0.f, 0.f, 0.f, 0.f), s1 = s0;
    float4 m0 = make_float4(-INFINITY, -INFINITY, -INFINITY, -INFINITY), m1 = m0;

    for (int nn = start + wave; nn < end; nn += 4) {
        const float4* xr = (const float4*)(x + (size_t)nn * 512);
        float4 a = xr[lane];
        float4 b = xr[lane + 64];
        float p = a.x * wa.x + a.y * wa.y + a.z * wa.z + a.w * wa.w
                + b.x * wb.x + b.y * wb.y + b.z * wb.z + b.w * wb.w;
        #pragma unroll
        for (int off = 32; off; off >>= 1) p += __shfl_down(p, off, 64);
        float wg = __shfl(p, 0, 64);
        wg = 1.f / (1.f + expf(-(wg + pb0)));
        s0.x += a.x * wg; s0.y += a.y * wg; s0.z += a.z * wg; s0.w += a.w * wg;
        s1.x += b.x * wg; s1.y += b.y * wg; s1.z += b.z * wg; s1.w += b.w * wg;
        m0.x = fmaxf(m0.x, a.x); m0.y = fmaxf(m0.y, a.y); m0.z = fmaxf(m0.z, a.z); m0.w = fmaxf(m0.w, a.w);
        m1.x = fmaxf(m1.x, b.x); m1.y = fmaxf(m1.y, b.y); m1.z = fmaxf(m1.z, b.z); m1.w = fmaxf(m1.w, b.w);
    }

    __shared__ float ls[4][1024];
    *(float4*)&ls[wave][lane * 4]       = s0;
    *(float4*)&ls[wave][256 + lane * 4] = s1;
    *(float4*)&ls[wave][512 + lane * 4] = m0;
    *(float4*)&ls[wave][768 + lane * 4] = m1;
    __syncthreads();

    float sa = ls[0][t] + ls[1][t] + ls[2][t] + ls[3][t];
    float sb = ls[0][t + 256] + ls[1][t + 256] + ls[2][t + 256] + ls[3][t + 256];
    float ma = fmaxf(fmaxf(ls[0][512 + t], ls[1][512 + t]), fmaxf(ls[2][512 + t], ls[3][512 + t]));
    float mb = fmaxf(fmaxf(ls[0][768 + t], ls[1][768 + t]), fmaxf(ls[2][768 + t], ls[3][768 + t]));
    if (start >= end) { ma = 0.f; mb = 0.f; }
    ushort h, l;
    size_t base = (size_t)g * 1024;
    split2(sa, h, l); phi[base + t] = h;       plo[base + t] = l;
    split2(sb, h, l); phi[base + 256 + t] = h; plo[base + 256 + t] = l;
    split2(ma, h, l); phi[base + 512 + t] = h; plo[base + 512 + t] = l;
    split2(mb, h, l); phi[base + 768 + t] = h; plo[base + 768 + t] = l;
}

// ---------------- launch ----------------

extern "C" void kernel_launch(void* const* d_in, const int* in_sizes, int n_in,
                              void* d_out, int out_size, void* d_ws, size_t ws_size,
                              hipStream_t stream) {
    const float* x0    = (const float*)d_in[0];
    const int*   ei    = (const int*)d_in[1];
    const int*   batch = (const int*)d_in[2];
    const float* W1 = (const float*)d_in[3];
    const float* b1 = (const float*)d_in[4];
    const float* W2 = (const float*)d_in[5];
    const float* b2 = (const float*)d_in[6];
    const float* W3 = (const float*)d_in[7];
    const float* b3 = (const float*)d_in[8];
    const float* pw = (const float*)d_in[9];
    const float* pb = (const float*)d_in[10];
    const float* Wo = (const float*)d_in[11];
    const float* bo = (const float*)d_in[12];
    float* out = (float*)d_out;

    // workspace layout (float units, 16B-aligned regions)
    float* ws = (float*)d_ws;
    size_t off = 0;
    float* bufB = ws + off; off += (size_t)NNODES * 512;                 // x3 fp32 (gatepool input)
    ushort* xh  = (ushort*)(ws + off); off += (size_t)NNODES * 256 / 2;  // activation bf16 table
    ushort* yhi = (ushort*)(ws + off); off += (size_t)NNODES * 256 / 2;  // agg out hi
    ushort* ylo = (ushort*)(ws + off); off += (size_t)NNODES * 256 / 2;  // agg out lo
    ushort* W1thi = (ushort*)(ws + off); off += 256 * 256 / 2;
    ushort* W1tlo = (ushort*)(ws + off); off += 256 * 256 / 2;
    ushort* W2thi = (ushort*)(ws + off); off += 256 * 256 / 2;
    ushort* W2tlo = (ushort*)(ws + off); off += 256 * 256 / 2;
    ushort* W3thi = (ushort*)(ws + off); off += 512 * 256 / 2;
    ushort* W3tlo = (ushort*)(ws + off); off += 512 * 256 / 2;
    ushort* Wothi = (ushort*)(ws + off); off += (size_t)FPOUT * 1024 / 2;
    ushort* Wotlo = (ushort*)(ws + off); off += (size_t)FPOUT * 1024 / 2;
    ushort* phi = (ushort*)(ws + off); off += (size_t)NGRAPH * 1024 / 2;
    ushort* plo = (ushort*)(ws + off); off += (size_t)NGRAPH * 1024 / 2;
    float* dis  = ws + off; off += NNODES;
    int*   degi = (int*)(ws + off); off += NNODES;
    int*   offs = (int*)(ws + off); off += (NNODES + 4);
    int*   curs = (int*)(ws + off); off += NNODES;
    int*   csr_src = (int*)(ws + off); off += NEDGES;
    float* csr_w   = ws + off; off += NEDGES;
    int*   partials = (int*)(ws + off); off += 256;

    const int NB_N = (NNODES + 255) / 256;   // 196
    const int NB_E = (NEDGES + 255) / 256;
    const int NB_A = NNODES / 8;             // 6250 blocks, wave = 2 nodes
    const int MB128 = (NNODES + 127) / 128;  // 391

    // weight transpose+split (LDS-tiled, coalesced)
    { dim3 g(256 / 32, 256 / 32);    wsplit_t<<<g, 256, 0, stream>>>(W1, W1thi, W1tlo, 256, 256); }
    { dim3 g(256 / 32, 256 / 32);    wsplit_t<<<g, 256, 0, stream>>>(W2, W2thi, W2tlo, 256, 256); }
    { dim3 g(512 / 32, 256 / 32);    wsplit_t<<<g, 256, 0, stream>>>(W3, W3thi, W3tlo, 256, 512); }
    { dim3 g(FPOUT / 32, 1024 / 32); wsplit_t<<<g, 256, 0, stream>>>(Wo, Wothi, Wotlo, 1024, FPOUT); }

    // CSR build
    zero_i32<<<NB_N, 256, 0, stream>>>(degi, NNODES);
    count_deg<<<NB_E, 256, 0, stream>>>(ei, degi, NEDGES);
    calc_dis<<<NB_N, 256, 0, stream>>>(degi, dis, NNODES);
    scanA<<<NB_N, 256, 0, stream>>>(degi, offs, partials, NNODES);
    scanB<<<1, 256, 0, stream>>>(partials, NB_N);
    scanC<<<NB_N, 256, 0, stream>>>(offs, partials, NNODES);
    copy_i32<<<NB_N, 256, 0, stream>>>(offs, curs, NNODES);
    fill_csr<<<NB_E, 256, 0, stream>>>(ei, dis, curs, csr_src, csr_w, NEDGES);

    // x0 -> bf16 table
    conv_bf16<<<(NNODES * 256 / 4 + 255) / 256, 256, 0, stream>>>(x0, xh, NNODES * 256 / 4);

    // layer 1: y = A_norm @ x0h ; x1h = bf16(relu(y @ W1 + b1))
    agg256b<<<NB_A, 256, 0, stream>>>(xh, yhi, ylo, dis, offs, csr_src, csr_w);
    {
        dim3 grid(H1 / 128, MB128);
        gemm_hl<<<grid, 256, 0, stream>>>(yhi, ylo, W1thi, W1tlo, nullptr, xh, b1, NNODES, H1, FIN, 1, 1);
    }
    // layer 2
    agg256b<<<NB_A, 256, 0, stream>>>(xh, yhi, ylo, dis, offs, csr_src, csr_w);
    {
        dim3 grid(H2 / 128, MB128);
        gemm_hl<<<grid, 256, 0, stream>>>(yhi, ylo, W2thi, W2tlo, nullptr, xh, b2, NNODES, H2, H1, 1, 1);
    }
    // layer 3: agg on x2h, GEMM 256->512 -> fp32 (gatepool input)
    agg256b<<<NB_A, 256, 0, stream>>>(xh, yhi, ylo, dis, offs, csr_src, csr_w);
    {
        dim3 grid(H3 / 128, MB128);
        gemm_hl<<<grid, 256, 0, stream>>>(yhi, ylo, W3thi, W3tlo, bufB, nullptr, b3, NNODES, H3, H2, 1, 0);
    }
    // fused gate+pool -> pooled bf16 hi/lo
    gatepool<<<NGRAPH, 256, 0, stream>>>(bufB, pw, pb, batch, phi, plo, NNODES);
    // head: out = relu(pooled @ Wo + bo) via MFMA
    {
        dim3 grid(FPOUT / 128, (NGRAPH + 127) / 128);
        gemm_hl<<<grid, 256, 0, stream>>>(phi, plo, Wothi, Wotlo, out, nullptr, bo, NGRAPH, FPOUT, 1024, 1, 0);
    }
}